// Round 6
// baseline (72.235 us; speedup 1.0000x reference)
//
#include <hip/hip_runtime.h>
#include <math.h>

// Problem constants (fixed by setup_inputs)
#define B_     32
#define K_     16
#define T_     30
#define KT_    480      // K*T pred points per batch
#define N_     128
#define NPN_   20       // nodes per polyline
#define NODES_ 2560     // N*NPN per batch
#define CH_    32       // node chunks per batch
#define CSZ_   80       // nodes per chunk = 4 whole polylines (yaw local)

#define PI_F      3.14159265358979323846f
#define TWO_PI_F  6.28318530717958647692f
#define YAW_TH_F  (PI_F / 3.0f)

// ws layout: float ws_part[B_][CH_][KT_]  (1.97 MB)
// R3 post-mortem: NO single-kernel cross-block reduction — device-scope
// fences/atomics cost ~60us on gfx950 (per-XCD L2 writeback). Keep 2 kernels.
// R5: ~50% of nodes masked -> LDS compaction (order-free, min commutes).
// R6: min over yaw-ok nodes commutes with sqrt(max(.,4)) -> phase 1 tracks
// only min d2 (9 ops, no sqrt); yaw-bad nodes can only matter if md2>4
// (P ~ 1e-6/pair) -> rare wave-uniform phase-2 fallback (exact). Early exit
// once all lanes have md2<=4 (answer is exactly the hoisted floor 2.0).

__global__ __launch_bounds__(256) void cm_main(
    const float* __restrict__ preds,   // (B, K, T, 2)
    const float* __restrict__ cn,      // (B, N, n, 2)
    const int*   __restrict__ cmask,   // (B, N, n)
    float*       __restrict__ ws_part) // (B, CH, KT)
{
  const int b   = blockIdx.x >> 5;          // / CH_
  const int c   = blockIdx.x & (CH_ - 1);
  const int tid = threadIdx.x;

  __shared__ float4 nd[CSZ_ + 8];   // compacted (-2x, -2y, a2, yaw) + inf pad
  __shared__ int    s_cnt;

  if (tid == 0) s_cnt = 0;
  __syncthreads();

  // ---- node prep + compaction (only unmasked nodes enter LDS) ----
  if (tid < CSZ_) {
    const int gn = c * CSZ_ + tid;
    const int mv = cmask[(size_t)b * NODES_ + gn];
    if (mv != 1) {
      const int j = gn % NPN_;
      const float2* cnb = (const float2*)cn + (size_t)b * NODES_;
      const float2 p = cnb[gn];
      float yaw = 0.0f;
      if (j != 0) {
        const float2 q = cnb[gn - 1];
        yaw = -atan2f(p.x - q.x, p.y - q.y);  // ref: -arctan2(dx, dy)
      }
      const float a2 = fmaf(p.x, p.x, p.y * p.y);
      const int pos = atomicAdd(&s_cnt, 1);   // LDS atomic, order-free for min
      nd[pos] = make_float4(-2.0f * p.x, -2.0f * p.y, a2, yaw);
    }
  }

  // ---- point prep in registers (2 points per thread) ----
  const int kt0 = tid;
  const int kt1 = tid + 256;                  // valid iff < 480
  const float2* pb = (const float2*)preds + (size_t)b * KT_;
  float4 p0, p1;
  {
    const float2 pp = pb[kt0];
    float pyaw = 0.0f;
    if ((kt0 % T_) != 0) {
      const float2 pq = pb[kt0 - 1];
      pyaw = -atan2f(pp.x - pq.x, pp.y - pq.y);
    }
    p0 = make_float4(pp.x, pp.y, fmaf(pp.x, pp.x, pp.y * pp.y), pyaw);
  }
  if (kt1 < KT_) {
    const float2 pp = pb[kt1];
    float pyaw = 0.0f;
    if ((kt1 % T_) != 0) {
      const float2 pq = pb[kt1 - 1];
      pyaw = -atan2f(pp.x - pq.x, pp.y - pq.y);
    }
    p1 = make_float4(pp.x, pp.y, fmaf(pp.x, pp.x, pp.y * pp.y), pyaw);
  } else {
    p1 = make_float4(0.f, 0.f, 0.f, 0.f);     // benign garbage lane
  }

  __syncthreads();
  const int cnt  = s_cnt;
  const int npad = (cnt + 7) & ~7;            // round up to unroll factor
  if (tid < npad - cnt)                       // inf sentinels: min no-ops
    nd[cnt + tid] = make_float4(0.f, 0.f, INFINITY, 0.f);
  __syncthreads();

  // ---- phase 1: min d2 over yaw-ok nodes only (no sqrt in loop) ----
  float md2_0 = INFINITY;
  float md2_1 = (kt1 < KT_) ? INFINITY : 0.0f;  // invalid lane: never blocks exit
  for (int i = 0; i < npad; i += 8) {
    #pragma unroll
    for (int j = 0; j < 8; ++j) {
      const float4 nv = nd[i + j];            // broadcast, conflict-free
      {
        float t = nv.z + p0.z;
        t = fmaf(nv.x, p0.x, t);
        t = fmaf(nv.y, p0.y, t);
        const float yd = nv.w - p0.w;
        const float a  = fminf(fabsf(yd), TWO_PI_F - fabsf(yd));
        md2_0 = fminf(md2_0, (a <= YAW_TH_F) ? t : INFINITY);
      }
      {
        float t = nv.z + p1.z;
        t = fmaf(nv.x, p1.x, t);
        t = fmaf(nv.y, p1.y, t);
        const float yd = nv.w - p1.w;
        const float a  = fminf(fabsf(yd), TWO_PI_F - fabsf(yd));
        md2_1 = fminf(md2_1, (a <= YAW_TH_F) ? t : INFINITY);
      }
    }
    // all 128 pairs at the floor (md2<=4 -> cost'==2 exactly)? done.
    if (__all((md2_0 <= 4.0f) && (md2_1 <= 4.0f))) break;
  }

  float m0 = __builtin_amdgcn_sqrtf(fmaxf(md2_0, 4.0f));
  float m1 = __builtin_amdgcn_sqrtf(fmaxf(md2_1, 4.0f));

  // ---- phase 2 (rare, wave-uniform): some lane has md2>4 -> a yaw-bad node
  // could beat it. Run the full original loop; exact for every lane.
  if (__any((md2_0 > 4.0f) || (md2_1 > 4.0f))) {
    float f0 = INFINITY, f1 = INFINITY;
    for (int i = 0; i < npad; ++i) {
      const float4 nv = nd[i];
      {
        float t = nv.z + p0.z;
        t = fmaf(nv.x, p0.x, t);
        t = fmaf(nv.y, p0.y, t);
        const float s  = __builtin_amdgcn_sqrtf(fmaxf(t, 4.0f));
        const float yd = nv.w - p0.w;
        const float a  = fminf(fabsf(yd), TWO_PI_F - fabsf(yd));
        f0 = fminf(f0, s + fmaxf(a - YAW_TH_F, 0.0f));
      }
      {
        float t = nv.z + p1.z;
        t = fmaf(nv.x, p1.x, t);
        t = fmaf(nv.y, p1.y, t);
        const float s  = __builtin_amdgcn_sqrtf(fmaxf(t, 4.0f));
        const float yd = nv.w - p1.w;
        const float a  = fminf(fabsf(yd), TWO_PI_F - fabsf(yd));
        f1 = fminf(f1, s + fmaxf(a - YAW_TH_F, 0.0f));
      }
    }
    m0 = fminf(m0, f0);
    m1 = fminf(m1, f1);
  }

  float* wp = ws_part + ((size_t)b * CH_ + c) * KT_;
  wp[kt0] = m0;
  if (kt1 < KT_) wp[kt1] = m1;
}

// Kernel 2: min over chunks (coalesced), subtract hoisted 2, sum over T.
__global__ __launch_bounds__(512) void cm_reduce(
    const float* __restrict__ ws_part, float* __restrict__ out)
{
  const int b   = blockIdx.x;
  const int tid = threadIdx.x;
  __shared__ float sc[KT_];

  if (tid < KT_) {
    const float* wp = ws_part + (size_t)b * CH_ * KT_;
    float m = INFINITY;
    #pragma unroll
    for (int c = 0; c < CH_; ++c) m = fminf(m, wp[c * KT_ + tid]);
    sc[tid] = m - 2.0f;                       // restore the hoisted -2
  }
  __syncthreads();

  if (tid < K_) {
    float s = 0.0f;
    #pragma unroll
    for (int t = 0; t < T_; ++t) s += sc[tid * T_ + t];
    out[b * K_ + tid] = s;
  }
}

extern "C" void kernel_launch(void* const* d_in, const int* in_sizes, int n_in,
                              void* d_out, int out_size, void* d_ws, size_t ws_size,
                              hipStream_t stream) {
  const float* preds = (const float*)d_in[0];
  const float* cn    = (const float*)d_in[1];
  const int*   cmask = (const int*)d_in[2];
  float* out = (float*)d_out;
  float* ws_part = (float*)d_ws;

  cm_main<<<dim3(B_ * CH_), dim3(256), 0, stream>>>(preds, cn, cmask, ws_part);
  cm_reduce<<<dim3(B_), dim3(512), 0, stream>>>(ws_part, out);
}

// Round 7
// 68.644 us; speedup vs baseline: 1.0523x; 1.0523x over previous
//
#include <hip/hip_runtime.h>
#include <math.h>

// Problem constants (fixed by setup_inputs)
#define B_     32
#define K_     16
#define T_     30
#define KT_    480      // K*T pred points per batch
#define N_     128
#define NPN_   20       // nodes per polyline
#define NODES_ 2560     // N*NPN per batch
#define CH_    32       // node chunks per batch
#define CSZ_   80       // nodes per chunk = 4 whole polylines (yaw local)

#define PI_F      3.14159265358979323846f
#define TWO_PI_F  6.28318530717958647692f
#define YAW_TH_F  (PI_F / 3.0f)

// ws layout: float ws_part[B_][CH_][KT_]  (1.97 MB)
//
// Session journal (validated structure — do not re-try):
//  R3: single-kernel cross-block reduction via device-scope fence/atomics
//      costs ~60us on gfx950 (per-XCD L2 writeback). 2-kernel split is ~5us.
//  R5: ~50% nodes masked -> LDS compaction (order-free, min commutes). WIN.
//  R6: sqrt-deferral + wave early-exit + rare phase-2 fallback: REGRESSION.
//      Early exit needs all 128 pairs floored (max of geometrics ~ 37/44
//      iters); phase-2 triggers for ~23% of waves; ballot broke unroll-8
//      scheduling. Loop is ISSUE-bound (R4->R5 delta matches 15-slot model),
//      so occupancy bumps gain ~0. This R5 form is the plateau.

__global__ __launch_bounds__(256) void cm_main(
    const float* __restrict__ preds,   // (B, K, T, 2)
    const float* __restrict__ cn,      // (B, N, n, 2)
    const int*   __restrict__ cmask,   // (B, N, n)
    float*       __restrict__ ws_part) // (B, CH, KT)
{
  const int b   = blockIdx.x >> 5;          // / CH_
  const int c   = blockIdx.x & (CH_ - 1);
  const int tid = threadIdx.x;

  __shared__ float4 nd[CSZ_ + 8];   // compacted (-2x, -2y, a2, yaw) + inf pad
  __shared__ int    s_cnt;

  if (tid == 0) s_cnt = 0;
  __syncthreads();

  // ---- node prep + compaction (only unmasked nodes enter LDS) ----
  if (tid < CSZ_) {
    const int gn = c * CSZ_ + tid;
    const int mv = cmask[(size_t)b * NODES_ + gn];
    if (mv != 1) {
      const int j = gn % NPN_;
      const float2* cnb = (const float2*)cn + (size_t)b * NODES_;
      const float2 p = cnb[gn];
      float yaw = 0.0f;
      if (j != 0) {
        const float2 q = cnb[gn - 1];
        yaw = -atan2f(p.x - q.x, p.y - q.y);  // ref: -arctan2(dx, dy)
      }
      const float a2 = fmaf(p.x, p.x, p.y * p.y);
      const int pos = atomicAdd(&s_cnt, 1);   // LDS atomic, order-free for min
      nd[pos] = make_float4(-2.0f * p.x, -2.0f * p.y, a2, yaw);
    }
  }

  // ---- point prep in registers (2 points per thread) ----
  const int kt0 = tid;
  const int kt1 = tid + 256;                  // valid iff < 480
  const float2* pb = (const float2*)preds + (size_t)b * KT_;
  float4 p0, p1;
  {
    const float2 pp = pb[kt0];
    float pyaw = 0.0f;
    if ((kt0 % T_) != 0) {
      const float2 pq = pb[kt0 - 1];
      pyaw = -atan2f(pp.x - pq.x, pp.y - pq.y);
    }
    p0 = make_float4(pp.x, pp.y, fmaf(pp.x, pp.x, pp.y * pp.y), pyaw);
  }
  if (kt1 < KT_) {
    const float2 pp = pb[kt1];
    float pyaw = 0.0f;
    if ((kt1 % T_) != 0) {
      const float2 pq = pb[kt1 - 1];
      pyaw = -atan2f(pp.x - pq.x, pp.y - pq.y);
    }
    p1 = make_float4(pp.x, pp.y, fmaf(pp.x, pp.x, pp.y * pp.y), pyaw);
  } else {
    p1 = make_float4(0.f, 0.f, 0.f, 0.f);     // benign garbage lane
  }

  __syncthreads();
  const int cnt  = s_cnt;
  const int npad = (cnt + 7) & ~7;            // round up to unroll factor
  if (tid < npad - cnt)                       // inf sentinels: min no-ops
    nd[cnt + tid] = make_float4(0.f, 0.f, INFINITY, 0.f);
  __syncthreads();

  // ---- main min loop over compacted nodes ----
  // cost' = sqrt(max(d2,4)) + relu(|dyaw|_wrap - pi/3)   [-2 hoisted]
  float m0 = INFINITY, m1 = INFINITY;
  for (int i = 0; i < npad; i += 8) {
    #pragma unroll
    for (int j = 0; j < 8; ++j) {
      const float4 nv = nd[i + j];            // broadcast, conflict-free
      {
        float t = nv.z + p0.z;
        t = fmaf(nv.x, p0.x, t);
        t = fmaf(nv.y, p0.y, t);
        t = fmaxf(t, 4.0f);
        const float s  = __builtin_amdgcn_sqrtf(t);
        const float yd = nv.w - p0.w;
        const float a  = fminf(fabsf(yd), TWO_PI_F - fabsf(yd));
        const float yc = fmaxf(a - YAW_TH_F, 0.0f);
        m0 = fminf(m0, s + yc);
      }
      {
        float t = nv.z + p1.z;
        t = fmaf(nv.x, p1.x, t);
        t = fmaf(nv.y, p1.y, t);
        t = fmaxf(t, 4.0f);
        const float s  = __builtin_amdgcn_sqrtf(t);
        const float yd = nv.w - p1.w;
        const float a  = fminf(fabsf(yd), TWO_PI_F - fabsf(yd));
        const float yc = fmaxf(a - YAW_TH_F, 0.0f);
        m1 = fminf(m1, s + yc);
      }
    }
  }

  float* wp = ws_part + ((size_t)b * CH_ + c) * KT_;
  wp[kt0] = m0;
  if (kt1 < KT_) wp[kt1] = m1;
}

// Kernel 2: min over chunks (coalesced), subtract hoisted 2, sum over T.
__global__ __launch_bounds__(512) void cm_reduce(
    const float* __restrict__ ws_part, float* __restrict__ out)
{
  const int b   = blockIdx.x;
  const int tid = threadIdx.x;
  __shared__ float sc[KT_];

  if (tid < KT_) {
    const float* wp = ws_part + (size_t)b * CH_ * KT_;
    float m = INFINITY;
    #pragma unroll
    for (int c = 0; c < CH_; ++c) m = fminf(m, wp[c * KT_ + tid]);
    sc[tid] = m - 2.0f;                       // restore the hoisted -2
  }
  __syncthreads();

  if (tid < K_) {
    float s = 0.0f;
    #pragma unroll
    for (int t = 0; t < T_; ++t) s += sc[tid * T_ + t];
    out[b * K_ + tid] = s;
  }
}

extern "C" void kernel_launch(void* const* d_in, const int* in_sizes, int n_in,
                              void* d_out, int out_size, void* d_ws, size_t ws_size,
                              hipStream_t stream) {
  const float* preds = (const float*)d_in[0];
  const float* cn    = (const float*)d_in[1];
  const int*   cmask = (const int*)d_in[2];
  float* out = (float*)d_out;
  float* ws_part = (float*)d_ws;

  cm_main<<<dim3(B_ * CH_), dim3(256), 0, stream>>>(preds, cn, cmask, ws_part);
  cm_reduce<<<dim3(B_), dim3(512), 0, stream>>>(ws_part, out);
}